// Round 1
// baseline (984.999 us; speedup 1.0000x reference)
//
#include <hip/hip_runtime.h>
#include <cstdint>
#include <cstddef>

// ---------------------------------------------------------------------------
// QLoRABigNet: 6 blocks x (linear, relu, linear, relu, linear) + LayerNorm.
// D=1024, BATCH=16384. 4-bit group-quant weights (GS=16), LoRA rank 32 merged
// exactly into dequantized W (W' = W + B@A). 18 bf16 MFMA GEMMs.
// R5 change: GEMM rewritten from 128^2/2-barrier (m97-structure, ~740 TF,
// at its known ~900 TF ceiling) to the 256^2 8-phase counted-vmcnt template
// (T2+T3+T4+T5). 8 waves (2Mx4N), BK=64, 128 KiB dbuf LDS, grid 256 = 1/CU.
// Schedule (derived, per K-tile kt; quadrant order (0,0),(1,0),(1,1),(0,1)):
//   ph1: ds A0sub+B0sub | issue B0(kt+1)->buf^1 | bar lgkm0 prio 16xMFMA bar
//   ph2: ds A1sub       | issue B1(kt+1)->buf^1 | ...
//   ph3: ds B1sub       | issue A0(kt+2)->buf   (A regions dead after ph2)
//   ph4: (no ds)        | issue A1(kt+2)->buf   | MFMA, vmcnt(4), bar
// vmcnt(4) once per tile = the 2 A-issues of kt+2 in flight; B(kt+1) has
// >=2-phase slack, A(kt+1) 5-6 phases (A = cold H stream, B = L2-hot W).
// ---------------------------------------------------------------------------

typedef short  bf16x8 __attribute__((ext_vector_type(8)));   // 8 bf16 (4 VGPRs)
typedef float  f32x4  __attribute__((ext_vector_type(4)));

__device__ __forceinline__ unsigned short f2bf(float f) {
  unsigned int u = __builtin_bit_cast(unsigned int, f);
  u += 0x7FFFu + ((u >> 16) & 1u);
  return (unsigned short)(u >> 16);
}

__device__ __forceinline__ void async_copy16(void* lds, const void* g) {
  __builtin_amdgcn_global_load_lds(
      (const __attribute__((address_space(1))) void*)(uintptr_t)(g),
      (__attribute__((address_space(3))) void*)(unsigned int)(uintptr_t)(lds),
      16, 0, 0);
}

// ---------------------------------------------------------------------------
// Dequant (+ LoRA merge). 4 independent int4 loads per thread (16 elements).
// grid: (256, 18), block 256.
// ---------------------------------------------------------------------------
__global__ __launch_bounds__(256) void dequant_kernel(
    const int* __restrict__ wq, const float* __restrict__ wn,
    const float* __restrict__ lora_a, const float* __restrict__ lora_b,
    unsigned short* __restrict__ Wbf) {
  const int l   = blockIdx.y;
  const int t   = threadIdx.x;
  const int blk = blockIdx.x;
  const long base = (long)l * 1048576;
  const float s = 2.0f / 15.0f;

  int4  q[4];
  float nrm[4];
#pragma unroll
  for (int k = 0; k < 4; ++k) {
    const int i4 = blk * 1024 + k * 256 + t;
    q[k]   = *(const int4*)(wq + base + (long)i4 * 4);
    nrm[k] = wn[l * 65536 + (i4 >> 2)];
  }

  float v[4][4];
#pragma unroll
  for (int k = 0; k < 4; ++k) {
    v[k][0] = ((float)q[k].x * s - 1.0f) * nrm[k];
    v[k][1] = ((float)q[k].y * s - 1.0f) * nrm[k];
    v[k][2] = ((float)q[k].z * s - 1.0f) * nrm[k];
    v[k][3] = ((float)q[k].w * s - 1.0f) * nrm[k];
  }

  const int slot = (l == 0) ? 0 : (l == 6) ? 1 : (l == 12) ? 2 : -1;
  if (slot >= 0) {
    const float* A = lora_a + slot * 32768 + t * 4;
    const float* B = lora_b + slot * 32768 + blk * 128;
#pragma unroll 8
    for (int r = 0; r < 32; ++r) {
      const float4 a4 = *(const float4*)(A + r * 1024);
#pragma unroll
      for (int k = 0; k < 4; ++k) {
        const float br = B[k * 32 + r];
        v[k][0] = fmaf(br, a4.x, v[k][0]);
        v[k][1] = fmaf(br, a4.y, v[k][1]);
        v[k][2] = fmaf(br, a4.z, v[k][2]);
        v[k][3] = fmaf(br, a4.w, v[k][3]);
      }
    }
  }

#pragma unroll
  for (int k = 0; k < 4; ++k) {
    unsigned short u[4] = {f2bf(v[k][0]), f2bf(v[k][1]),
                           f2bf(v[k][2]), f2bf(v[k][3])};
    const long e0 = base + ((long)blk * 1024 + k * 256 + t) * 4;
    *(uint2*)(Wbf + e0) = *(uint2*)u;
  }
}

// ---------------------------------------------------------------------------
// fp32 -> bf16 for the initial x. grid 4096, block 256 (16 elems/thread).
// ---------------------------------------------------------------------------
__global__ __launch_bounds__(256) void cvt_bf16_kernel(
    const float* __restrict__ in, unsigned short* __restrict__ out) {
  const long b0 = (long)blockIdx.x * 4096 + threadIdx.x * 4;
  float4 v[4];
#pragma unroll
  for (int k = 0; k < 4; ++k) v[k] = *(const float4*)(in + b0 + k * 1024);
#pragma unroll
  for (int k = 0; k < 4; ++k) {
    unsigned short u[4] = {f2bf(v[k].x), f2bf(v[k].y), f2bf(v[k].z), f2bf(v[k].w)};
    *(ushort4*)(out + b0 + k * 1024) = *(ushort4*)u;
  }
}

// ---------------------------------------------------------------------------
// GEMM: out[m][n] = sum_k H[m][k] * W[n][k] + bias[n]
// M=16384, N=1024, K=1024. 256x256 tile, BK=64, 8 waves (2Mx4N), per-wave
// 128x64 output (acc[8][4] f32x4). 8-phase counted-vmcnt schedule (header).
// LDS 128 KiB dynamic: buf0 A[0,32K) B[32K,64K); buf1 at +64K.
// Chunk swizzle (both sides): row r, 16B chunk c stored at chunk c^(r&7).
// XCD swizzle: block b -> s=(b&7)*32+b/8; each XCD: 8 m-tiles x all 4 n-tiles.
// MODE 0: relu, bf16 out. MODE 1: no relu, fp32 out.
// ---------------------------------------------------------------------------
template <int MODE>
__global__ __launch_bounds__(512, 2) void gemm8_kernel(
    const unsigned short* __restrict__ H,   // [16384][1024] bf16
    const unsigned short* __restrict__ W,   // [1024][1024] bf16 (layer slice)
    const float* __restrict__ bias,         // [1024]
    unsigned short* __restrict__ outb,      // MODE 0
    float* __restrict__ outf) {             // MODE 1
  extern __shared__ char smem[];

  const int tid = threadIdx.x;
  const int w   = tid >> 6;        // wave 0..7
  const int ln  = tid & 63;
  const int wm  = w >> 2;          // 0..1  (M half)
  const int wn  = w & 3;           // 0..3  (N quarter)

  const int b  = blockIdx.x;
  const int s  = (b & 7) * 32 + (b >> 3);   // bijective XCD swizzle (256%8==0)
  const int m0 = (s >> 2) * 256;
  const int n0 = (s & 3) * 256;

  // staging: thread t covers row (t>>3) of a 64-row round, phys chunk t&7;
  // stored global chunk gc = (t&7) ^ ((t>>3)&7)  (w*8 == 0 mod 8)
  const int gc    = (ln & 7) ^ ((ln >> 3) & 7);
  const int rowst = w * 8 + (ln >> 3);
  const unsigned eA = (unsigned)(m0 + rowst) * 1024u + gc * 8;
  const unsigned eB = (unsigned)(n0 + rowst) * 1024u + gc * 8;
  const int wofs = w * 1024;       // wave-uniform LDS dest base offset

  // fragment reads: row base + swizzled chunk (kk*4+quad)^(lrow&7)
  const int quad = ln >> 4;
  const int lrow = ln & 15;
  const int sw   = lrow & 7;
  const int c0   = ((quad)     ^ sw) * 16;
  const int c1   = ((quad + 4) ^ sw) * 16;
  const int aoff = (wm * 128 + lrow) * 128;
  const int boff = (wn * 64  + lrow) * 128;

#define STAGE_A(T_, D_, F_, J_)                                                \
  async_copy16(smem + (D_) * 65536 + (F_) * 16384 + (J_) * 8192 + wofs,        \
               H + eA + (unsigned)((T_) * 64 + ((F_) * 128 + (J_) * 64) * 1024))
#define STAGE_B(T_, D_, F_, J_)                                                \
  async_copy16(smem + (D_) * 65536 + 32768 + (F_) * 16384 + (J_) * 8192 + wofs,\
               W + eB + (unsigned)((T_) * 64 + ((F_) * 128 + (J_) * 64) * 1024))
#define MM16(AV, BV, I0, J0)                                                   \
  {                                                                            \
    _Pragma("unroll") for (int i_ = 0; i_ < 4; ++i_) {                         \
      _Pragma("unroll") for (int j_ = 0; j_ < 2; ++j_) {                       \
        acc[(I0) + i_][(J0) + j_] = __builtin_amdgcn_mfma_f32_16x16x32_bf16(   \
            AV[i_][0], BV[j_][0], acc[(I0) + i_][(J0) + j_], 0, 0, 0);         \
        acc[(I0) + i_][(J0) + j_] = __builtin_amdgcn_mfma_f32_16x16x32_bf16(   \
            AV[i_][1], BV[j_][1], acc[(I0) + i_][(J0) + j_], 0, 0, 0);         \
      }                                                                        \
    }                                                                          \
  }
#define LDSUB4(DST, BASE, OFF)                                                 \
  {                                                                            \
    _Pragma("unroll") for (int i_ = 0; i_ < 4; ++i_) {                         \
      DST[i_][0] = *(const bf16x8*)((BASE) + (OFF) + i_ * 2048 + c0);          \
      DST[i_][1] = *(const bf16x8*)((BASE) + (OFF) + i_ * 2048 + c1);          \
    }                                                                          \
  }
#define LDSUB2(DST, BASE, OFF)                                                 \
  {                                                                            \
    _Pragma("unroll") for (int j_ = 0; j_ < 2; ++j_) {                         \
      DST[j_][0] = *(const bf16x8*)((BASE) + (OFF) + j_ * 2048 + c0);          \
      DST[j_][1] = *(const bf16x8*)((BASE) + (OFF) + j_ * 2048 + c1);          \
    }                                                                          \
  }

  f32x4 acc[8][4];
#pragma unroll
  for (int i = 0; i < 8; ++i)
#pragma unroll
    for (int j = 0; j < 4; ++j) acc[i][j] = (f32x4){0.f, 0.f, 0.f, 0.f};

  // prologue: tile0 (A0,A1,B0,B1) -> buf0; tile1 (A0,A1) -> buf1.
  // Issue order defines vmcnt counting: first 8 loads = all of tile 0.
  STAGE_A(0, 0, 0, 0); STAGE_A(0, 0, 0, 1);
  STAGE_A(0, 0, 1, 0); STAGE_A(0, 0, 1, 1);
  STAGE_B(0, 0, 0, 0); STAGE_B(0, 0, 0, 1);
  STAGE_B(0, 0, 1, 0); STAGE_B(0, 0, 1, 1);
  asm volatile("" ::: "memory");    // pin tile0-group before tile1-group
  STAGE_A(1, 1, 0, 0); STAGE_A(1, 1, 0, 1);
  STAGE_A(1, 1, 1, 0); STAGE_A(1, 1, 1, 1);
  asm volatile("s_waitcnt vmcnt(4)" ::: "memory");   // tile 0 landed
  __builtin_amdgcn_s_barrier();

  bf16x8 a0[4][2], a1[4][2], bb[2][2];

#pragma unroll 2
  for (int kt = 0; kt < 16; ++kt) {
    const int BUF = kt & 1;
    const char* At = smem + BUF * 65536;
    const char* Bt = At + 32768;
    const int  nb = BUF ^ 1;
    const bool ib = (kt < 15);   // issue B(kt+1)
    const bool ia = (kt < 14);   // issue A(kt+2)

    // ---- phase 1: q(0,0) -------------------------------------------------
    LDSUB4(a0, At, aoff);
    LDSUB2(bb, Bt, boff);
    if (ib) { STAGE_B(kt + 1, nb, 0, 0); STAGE_B(kt + 1, nb, 0, 1); }
    __builtin_amdgcn_s_barrier();
    asm volatile("s_waitcnt lgkmcnt(0)" ::: "memory");
    __builtin_amdgcn_s_setprio(1);
    MM16(a0, bb, 0, 0);
    __builtin_amdgcn_s_setprio(0);
    __builtin_amdgcn_s_barrier();

    // ---- phase 2: q(1,0) -------------------------------------------------
    LDSUB4(a1, At, aoff + 8192);
    if (ib) { STAGE_B(kt + 1, nb, 1, 0); STAGE_B(kt + 1, nb, 1, 1); }
    __builtin_amdgcn_s_barrier();
    asm volatile("s_waitcnt lgkmcnt(0)" ::: "memory");
    __builtin_amdgcn_s_setprio(1);
    MM16(a1, bb, 4, 0);
    __builtin_amdgcn_s_setprio(0);
    __builtin_amdgcn_s_barrier();
    // A-halves of buf[BUF] now dead (all A ds_reads completed by all waves)

    // ---- phase 3: q(1,1) -------------------------------------------------
    LDSUB2(bb, Bt, boff + 4096);
    if (ia) { STAGE_A(kt + 2, BUF, 0, 0); STAGE_A(kt + 2, BUF, 0, 1); }
    __builtin_amdgcn_s_barrier();
    asm volatile("s_waitcnt lgkmcnt(0)" ::: "memory");
    __builtin_amdgcn_s_setprio(1);
    MM16(a1, bb, 4, 2);
    __builtin_amdgcn_s_setprio(0);
    __builtin_amdgcn_s_barrier();

    // ---- phase 4: q(0,1) -------------------------------------------------
    if (ia) { STAGE_A(kt + 2, BUF, 1, 0); STAGE_A(kt + 2, BUF, 1, 1); }
    __builtin_amdgcn_s_barrier();
    __builtin_amdgcn_s_setprio(1);
    MM16(a0, bb, 0, 2);
    __builtin_amdgcn_s_setprio(0);
    if (kt < 14) {
      asm volatile("s_waitcnt vmcnt(4)" ::: "memory");  // allow A(kt+2) x2
    } else if (kt == 14) {
      asm volatile("s_waitcnt vmcnt(0)" ::: "memory");  // tail drain
    }
    __builtin_amdgcn_s_barrier();
  }

#undef LDSUB2
#undef LDSUB4
#undef MM16
#undef STAGE_B
#undef STAGE_A

  // epilogue: C/D layout col=lane&15, row=quad*4+reg
#pragma unroll
  for (int nt = 0; nt < 4; ++nt) {
    const int n = n0 + wn * 64 + nt * 16 + lrow;
    const float bs = bias[n];
#pragma unroll
    for (int mt = 0; mt < 8; ++mt) {
      const int mb = m0 + wm * 128 + mt * 16 + quad * 4;
      const f32x4 v = acc[mt][nt];
#pragma unroll
      for (int r = 0; r < 4; ++r) {
        float o = v[r] + bs;
        if (MODE == 0) {
          o = fmaxf(o, 0.0f);
          outb[(size_t)(mb + r) * 1024 + n] = f2bf(o);
        } else {
          outf[(size_t)(mb + r) * 1024 + n] = o;
        }
      }
    }
  }
}

// ---------------------------------------------------------------------------
// LayerNorm over rows of 1024. One WAVE per row (4 rows/block).
// grid 4096, block 256.
// ---------------------------------------------------------------------------
__global__ __launch_bounds__(256) void ln_kernel(
    const float* __restrict__ in, const float* __restrict__ lnw,
    const float* __restrict__ lnb, unsigned short* __restrict__ outb,
    float* __restrict__ outf, int wf32) {
  const int wv = threadIdx.x >> 6;
  const int ln = threadIdx.x & 63;
  const int row = blockIdx.x * 4 + wv;
  const float* p = in + (size_t)row * 1024;

  float4 v[4];
  float s = 0.f, q = 0.f;
#pragma unroll
  for (int c = 0; c < 4; ++c) {
    v[c] = *(const float4*)(p + c * 256 + ln * 4);
    s += v[c].x + v[c].y + v[c].z + v[c].w;
    q += v[c].x * v[c].x + v[c].y * v[c].y + v[c].z * v[c].z + v[c].w * v[c].w;
  }
#pragma unroll
  for (int off = 32; off; off >>= 1) {
    s += __shfl_xor(s, off);
    q += __shfl_xor(q, off);
  }
  const float mu  = s * (1.0f / 1024.0f);
  const float var = q * (1.0f / 1024.0f) - mu * mu;
  const float rs  = rsqrtf(var + 1e-5f);

#pragma unroll
  for (int c = 0; c < 4; ++c) {
    const int col = c * 256 + ln * 4;
    const float4 w4 = *(const float4*)(lnw + col);
    const float4 b4 = *(const float4*)(lnb + col);
    const float y0 = (v[c].x - mu) * rs * w4.x + b4.x;
    const float y1 = (v[c].y - mu) * rs * w4.y + b4.y;
    const float y2 = (v[c].z - mu) * rs * w4.z + b4.z;
    const float y3 = (v[c].w - mu) * rs * w4.w + b4.w;
    unsigned short u[4] = {f2bf(y0), f2bf(y1), f2bf(y2), f2bf(y3)};
    *(ushort4*)(outb + (size_t)row * 1024 + col) = *(ushort4*)u;
    if (wf32) {
      float4 y = make_float4(y0, y1, y2, y3);
      *(float4*)(outf + (size_t)row * 1024 + col) = y;
    }
  }
}

// ---------------------------------------------------------------------------
extern "C" void kernel_launch(void* const* d_in, const int* in_sizes, int n_in,
                              void* d_out, int out_size, void* d_ws, size_t ws_size,
                              hipStream_t stream) {
  const float* x    = (const float*)d_in[0];
  const int*   wq   = (const int*)d_in[1];
  const float* wn   = (const float*)d_in[2];
  const float* bias = (const float*)d_in[3];
  const float* la   = (const float*)d_in[4];
  const float* lb   = (const float*)d_in[5];
  const float* lnw  = (const float*)d_in[6];
  const float* lnb  = (const float*)d_in[7];
  float* out = (float*)d_out;

  char* ws = (char*)d_ws;
  unsigned short* Wbf = (unsigned short*)ws;                         // 37.75 MB
  unsigned short* hA  = (unsigned short*)(ws + 37748736);            // 32 MB
  unsigned short* hB  = (unsigned short*)(ws + 37748736 + 33554432); // 32 MB

  dequant_kernel<<<dim3(256, 18), 256, 0, stream>>>(wq, wn, la, lb, Wbf);
  cvt_bf16_kernel<<<4096, 256, 0, stream>>>(x, hA);

  for (int blk = 0; blk < 6; ++blk) {
    const int l = blk * 3;
    gemm8_kernel<0><<<256, 512, 131072, stream>>>(
        hA, Wbf + (size_t)l * 1048576, bias + l * 1024, hB, nullptr);
    gemm8_kernel<0><<<256, 512, 131072, stream>>>(
        hB, Wbf + (size_t)(l + 1) * 1048576, bias + (l + 1) * 1024, hA, nullptr);
    gemm8_kernel<1><<<256, 512, 131072, stream>>>(
        hA, Wbf + (size_t)(l + 2) * 1048576, bias + (l + 2) * 1024, nullptr, out);
    ln_kernel<<<4096, 256, 0, stream>>>(
        out, lnw + blk * 1024, lnb + blk * 1024, hA, out, blk == 5 ? 1 : 0);
  }
}